// Round 7
// baseline (213.862 us; speedup 1.0000x reference)
//
#include <hip/hip_runtime.h>
#include <hip/hip_bf16.h>
#include <hip/hip_fp16.h>
#include <math.h>

// (B, D, H, W, K) = (32, 256, 64, 64, 64); N = H*W = 4096
#define BB 32
#define DD 256
#define NN 4096
#define KK 64
#define EPSV 1e-8f
#define XSTR 264   // xnd row stride (shorts): 528 B = 16B-aligned, bank-rotating

typedef __attribute__((ext_vector_type(8))) short short8;   // 8 bf16
typedef __attribute__((ext_vector_type(4))) float f32x4;

__device__ __forceinline__ unsigned int bf16pair(float a, float b) {
    __hip_bfloat162 h = __float22bfloat162_rn(make_float2(a, b));  // v_cvt_pk_bf16_f32 (RNE)
    return *(unsigned int*)&h;
}
__device__ __forceinline__ unsigned short bf16one(float a) {
    unsigned int ua = __float_as_uint(a);
    ua += 0x7fffu + ((ua >> 16) & 1u);
    return (unsigned short)(ua >> 16);
}
__device__ __forceinline__ unsigned int f16pair(float a, float b) {
    __half2 h = __float22half2_rn(make_float2(a, b));  // v_cvt_pk_f16_f32 (RNE)
    return *(unsigned int*)&h;
}

// stage one 4d x 4n register subtile into xnd (n-major) + accumulate ||x||^2.
// R14: xdn path deleted entirely (agg A-operand comes from global, L2-hot).
__device__ __forceinline__ void stage_xnd(int dbase, int n4, const float4* rr,
                                          unsigned short* xnd, f32x4& ssn) {
    float4 r0 = rr[0], r1 = rr[1], r2 = rr[2], r3 = rr[3];
    ssn.x = fmaf(r0.x, r0.x, ssn.x); ssn.x = fmaf(r1.x, r1.x, ssn.x);
    ssn.x = fmaf(r2.x, r2.x, ssn.x); ssn.x = fmaf(r3.x, r3.x, ssn.x);
    ssn.y = fmaf(r0.y, r0.y, ssn.y); ssn.y = fmaf(r1.y, r1.y, ssn.y);
    ssn.y = fmaf(r2.y, r2.y, ssn.y); ssn.y = fmaf(r3.y, r3.y, ssn.y);
    ssn.z = fmaf(r0.z, r0.z, ssn.z); ssn.z = fmaf(r1.z, r1.z, ssn.z);
    ssn.z = fmaf(r2.z, r2.z, ssn.z); ssn.z = fmaf(r3.z, r3.z, ssn.z);
    ssn.w = fmaf(r0.w, r0.w, ssn.w); ssn.w = fmaf(r1.w, r1.w, ssn.w);
    ssn.w = fmaf(r2.w, r2.w, ssn.w); ssn.w = fmaf(r3.w, r3.w, ssn.w);
    float col[4][4] = {{r0.x, r1.x, r2.x, r3.x},
                       {r0.y, r1.y, r2.y, r3.y},
                       {r0.z, r1.z, r2.z, r3.z},
                       {r0.w, r1.w, r2.w, r3.w}};
#pragma unroll
    for (int j = 0; j < 4; j++) {
        int n = n4 + j;
        uint2 u;
        u.x = bf16pair(col[j][0], col[j][1]);
        u.y = bf16pair(col[j][2], col[j][3]);
        int blk = (dbase >> 3) ^ ((n >> 2) & 3);
        *(uint2*)(xnd + n * XSTR + (blk << 3) + (dbase & 7)) = u;
    }
}

// ---------------- fused: L-GEMM -> softmax -> agg-GEMM ----------------
// R14 = phase-serialization attack (R12/R13 showed TLP and HBM bytes are NOT
// the binder; per-pass issue work ~1K wave-cyc vs ~30K cyc/pass measured ->
// barrier convoys + serial phases dominate):
//   - xdn_s DELETED; agg A-operand read from global f32 (L2-hot, same values
//     -> bit-identical bf16 after cvt). ax = 16 VGPRs only, issued pre-E so
//     latency hides in the barrier wait (R9's failure was 64-reg ax in a
//     4-wave structure at cap 128 -> spill; here peak ~110 <= 128).
//   - xnd_s DOUBLE-BUFFERED with the freed LDS: staging(p+1) has no WAR on
//     pass p readers -> barriers A and B deleted. 2 barriers/pass (D, E).
//     Staging ds_writes drain in background under L-GEMM.
//   - at_s packed to stride 64 (XOR swizzle keeps b128 reads 2-way = free).
//   - LDS: 2*33792 + 8192 + 2048 + 2048 = 79872 (= R11's verified alloc).
//   - load pipeline: ld[4] (16 regs): hi(p+1) issued phase 1, lo(p+2) issued
//     phase 6; rn4 single-buffered (readers pre-D, writers post-D: fenced).
// Hazard audit (all cross-pass pairs fenced): xnd write(p,ph1/ph6) vs read
// L-GEMM(p-1): D(p-1)/E(p-1). rn4 write(ph6,p) vs read softmax(p): D(p);
// vs read softmax(p+1): E(p). red_s w(ph4) vs r(ph6): D(p); w(p+1) vs r(p):
// E(p). at_s w(ph6) vs r agg(p): E(p); w(p+1) vs r agg(p): D(p+1).
__global__ __launch_bounds__(512, 2) void k_fused(const float* __restrict__ X,
                                                  const float* __restrict__ C,
                                                  __half* __restrict__ P,
                                                  float* __restrict__ Sp) {
    __shared__ unsigned short xnd_s[2 * 64 * XSTR];  // double-buffered [n][d] bf16, 67584 B
    __shared__ unsigned short at_s[KK * 64];         // [k][n] bf16, stride-64 XOR swz, 8192 B
    __shared__ float rn4[8 * 64];                    // per-wave partial ||x_n||^2 (single buf)
    __shared__ float red_s[8 * 64];                  // per-wave exp-sum; reused for S-combine

    int t = threadIdx.x;
    int b = blockIdx.x >> 4, chunk = blockIdx.x & 15;
    int w = t >> 6, lane = t & 63, c = lane & 15, g = lane >> 4;
    int q2 = t >> 4;               // 4w + g in [0,32): staging row group
    int n4 = c * 4;
    int kw = w & 3, nh = w >> 2;   // L-GEMM split: k-tile kw, n-half nh

    const float* Xb = X + (size_t)b * DD * NN + chunk * 256;

    // ---- codeword fragments in registers + on-the-fly row norm ----
    short8 cnf[8];
    {
        int k = 16 * kw + c;
        const float* cp = C + k * DD;
        float4 v0[8], v1[8];
        float ss = 0.f;
#pragma unroll
        for (int ks = 0; ks < 8; ks++) {
            v0[ks] = *(const float4*)(cp + 32 * ks + 8 * g);
            v1[ks] = *(const float4*)(cp + 32 * ks + 8 * g + 4);
            ss = fmaf(v0[ks].x, v0[ks].x, ss); ss = fmaf(v0[ks].y, v0[ks].y, ss);
            ss = fmaf(v0[ks].z, v0[ks].z, ss); ss = fmaf(v0[ks].w, v0[ks].w, ss);
            ss = fmaf(v1[ks].x, v1[ks].x, ss); ss = fmaf(v1[ks].y, v1[ks].y, ss);
            ss = fmaf(v1[ks].z, v1[ks].z, ss); ss = fmaf(v1[ks].w, v1[ks].w, ss);
        }
        ss += __shfl_xor(ss, 16);
        ss += __shfl_xor(ss, 32);
        float r = 1.f / fmaxf(sqrtf(ss), EPSV);
#pragma unroll
        for (int ks = 0; ks < 8; ks++) {
            uint4 u;
            u.x = bf16pair(v0[ks].x * r, v0[ks].y * r);
            u.y = bf16pair(v0[ks].z * r, v0[ks].w * r);
            u.z = bf16pair(v1[ks].x * r, v1[ks].y * r);
            u.w = bf16pair(v1[ks].z * r, v1[ks].w * r);
            cnf[ks] = *(short8*)&u;
        }
    }

    // ---- prologue: stage pass 0 into buf0 + rn4; issue lo(1) ----
    float4 ld[4];
    {
        const float* xb = Xb + (size_t)(q2 * 4) * NN + n4;
#pragma unroll
        for (int j = 0; j < 4; j++) ld[j] = *(const float4*)(xb + (size_t)j * NN);
    }
    {
        f32x4 ssn0 = (f32x4){0.f, 0.f, 0.f, 0.f};
        stage_xnd(q2 * 4, n4, ld, xnd_s, ssn0);
        const float* xb = Xb + (size_t)(q2 * 4 + 128) * NN + n4;
#pragma unroll
        for (int j = 0; j < 4; j++) ld[j] = *(const float4*)(xb + (size_t)j * NN);
        stage_xnd(q2 * 4 + 128, n4, ld, xnd_s, ssn0);
        ssn0.x += __shfl_xor(ssn0.x, 16); ssn0.x += __shfl_xor(ssn0.x, 32);
        ssn0.y += __shfl_xor(ssn0.y, 16); ssn0.y += __shfl_xor(ssn0.y, 32);
        ssn0.z += __shfl_xor(ssn0.z, 16); ssn0.z += __shfl_xor(ssn0.z, 32);
        ssn0.w += __shfl_xor(ssn0.w, 16); ssn0.w += __shfl_xor(ssn0.w, 32);
        if (g == 0) *(f32x4*)(rn4 + w * 64 + n4) = ssn0;
    }
    {
        const float* xb = Xb + (size_t)(q2 * 4) * NN + 64 + n4;
#pragma unroll
        for (int j = 0; j < 4; j++) ld[j] = *(const float4*)(xb + (size_t)j * NN);
    }
    __syncthreads();  // buf0 + rn4 visible for pass 0

    f32x4 eacc[2][4];  // d = 32w + dt*16, k = kt*16
#pragma unroll
    for (int dt = 0; dt < 2; dt++)
#pragma unroll
        for (int kt = 0; kt < 4; kt++) eacc[dt][kt] = (f32x4){0.f, 0.f, 0.f, 0.f};
    float s_acc[4] = {0.f, 0.f, 0.f, 0.f};

    for (int p = 0; p < 4; p++) {
        unsigned short* xc = xnd_s + (p & 1) * (64 * XSTR);        // current buffer
        unsigned short* xn = xnd_s + ((p & 1) ^ 1) * (64 * XSTR);  // next buffer

        // ---- phase 1: stage lo(p+1) (no barrier: readers fenced 2 passes
        //      back); issue hi(p+1); ds_writes drain under L-GEMM ----
        f32x4 ssn = (f32x4){0.f, 0.f, 0.f, 0.f};
        if (p < 3) {
            stage_xnd(q2 * 4, n4, ld, xn, ssn);
            const float* xb = Xb + (size_t)(q2 * 4 + 128) * NN + (p + 1) * 64 + n4;
#pragma unroll
            for (int j = 0; j < 4; j++) ld[j] = *(const float4*)(xb + (size_t)j * NN);
        }

        // ---- L-GEMM: Lt[16kw..+16 k][32nh..+32 n] from xc ----
        f32x4 lacc[2];
#pragma unroll
        for (int nt = 0; nt < 2; nt++) lacc[nt] = (f32x4){0.f, 0.f, 0.f, 0.f};
#pragma unroll
        for (int ks = 0; ks < 8; ks++) {
            short8 af = cnf[ks];
#pragma unroll
            for (int nt = 0; nt < 2; nt++) {
                int n = 32 * nh + nt * 16 + c;
                short8 bf = *(const short8*)(xc + n * XSTR +
                                             (((4 * ks + g) ^ ((n >> 2) & 3)) << 3));
                lacc[nt] = __builtin_amdgcn_mfma_f32_16x16x32_bf16(af, bf, lacc[nt], 0, 0, 0);
            }
        }

        // ---- softmax partials (no max-subtract: cosine sims in [-1,1]) ----
        float lv[2][4];
#pragma unroll
        for (int nt = 0; nt < 2; nt++) {
            int n = 32 * nh + nt * 16 + c;
            float ssq = rn4[n] + rn4[64 + n] + rn4[128 + n] + rn4[192 + n] +
                        rn4[256 + n] + rn4[320 + n] + rn4[384 + n] + rn4[448 + n];
            float rn = 1.f / fmaxf(sqrtf(ssq), EPSV);
            float s = 0.f;
#pragma unroll
            for (int r = 0; r < 4; r++) {
                lv[nt][r] = __expf(lacc[nt][r] * rn);
                s += lv[nt][r];
            }
            s += __shfl_xor(s, 16);
            s += __shfl_xor(s, 32);
            if (g == 0) red_s[w * 64 + n] = s;
        }
        __syncthreads();  // (D) red_s visible; also fences rn4 update below

        // ---- denominators + A write (at_s, stride-64 XOR swizzle) ----
#pragma unroll
        for (int nt = 0; nt < 2; nt++) {
            int n = 32 * nh + nt * 16 + c;
            float denom = red_s[(4 * nh + 0) * 64 + n] + red_s[(4 * nh + 1) * 64 + n] +
                          red_s[(4 * nh + 2) * 64 + n] + red_s[(4 * nh + 3) * 64 + n];
            float inv = 1.f / denom;
#pragma unroll
            for (int r = 0; r < 4; r++) {
                float a = lv[nt][r] * inv;
                s_acc[r] += a;
                int k = 16 * kw + 4 * g + r;
                at_s[k * 64 + ((((n >> 3) ^ (k & 7)) << 3) | (n & 7))] = bf16one(a);
            }
        }

        // ---- phase 6: stage hi(p+1); finish ssn; rn4 update (post-D safe:
        //      pass-p readers were pre-D); issue lo(p+2) ----
        if (p < 3) {
            stage_xnd(q2 * 4 + 128, n4, ld, xn, ssn);
            ssn.x += __shfl_xor(ssn.x, 16); ssn.x += __shfl_xor(ssn.x, 32);
            ssn.y += __shfl_xor(ssn.y, 16); ssn.y += __shfl_xor(ssn.y, 32);
            ssn.z += __shfl_xor(ssn.z, 16); ssn.z += __shfl_xor(ssn.z, 32);
            ssn.w += __shfl_xor(ssn.w, 16); ssn.w += __shfl_xor(ssn.w, 32);
            if (g == 0) *(f32x4*)(rn4 + w * 64 + n4) = ssn;
            if (p < 2) {
                const float* xb = Xb + (size_t)(q2 * 4) * NN + (p + 2) * 64 + n4;
#pragma unroll
                for (int j = 0; j < 4; j++) ld[j] = *(const float4*)(xb + (size_t)j * NN);
            }
        }

        // ---- issue agg A-operand ks2=0 (global f32, L2-hot) pre-E:
        //      latency hides in the barrier wait ----
        float4 ax[4];
#pragma unroll
        for (int dt = 0; dt < 2; dt++) {
            const float* xa = Xb + (size_t)(32 * w + dt * 16 + c) * NN + p * 64 + 8 * g;
            ax[2 * dt + 0] = *(const float4*)(xa);
            ax[2 * dt + 1] = *(const float4*)(xa + 4);
        }
        __syncthreads();  // (E) at_s visible

        // ---- agg-GEMM: Et[d=32w..+32][k] += sum_n X[n][d]*A[n][k] ----
        // ks2 = 0
        short8 bk[4];
#pragma unroll
        for (int kt = 0; kt < 4; kt++) {
            int k = kt * 16 + c;
            bk[kt] = *(const short8*)(at_s + k * 64 + (((0 + g) ^ (k & 7)) << 3));
        }
        short8 af0[2];
#pragma unroll
        for (int dt = 0; dt < 2; dt++) {
            float4 f0 = ax[2 * dt + 0], f1 = ax[2 * dt + 1];
            uint4 u;
            u.x = bf16pair(f0.x, f0.y);
            u.y = bf16pair(f0.z, f0.w);
            u.z = bf16pair(f1.x, f1.y);
            u.w = bf16pair(f1.z, f1.w);
            af0[dt] = *(short8*)&u;
        }
        // issue ks2=1 loads into ax (regs free after cvt)
#pragma unroll
        for (int dt = 0; dt < 2; dt++) {
            const float* xa = Xb + (size_t)(32 * w + dt * 16 + c) * NN + p * 64 + 32 + 8 * g;
            ax[2 * dt + 0] = *(const float4*)(xa);
            ax[2 * dt + 1] = *(const float4*)(xa + 4);
        }
#pragma unroll
        for (int dt = 0; dt < 2; dt++)
#pragma unroll
            for (int kt = 0; kt < 4; kt++)
                eacc[dt][kt] =
                    __builtin_amdgcn_mfma_f32_16x16x32_bf16(af0[dt], bk[kt], eacc[dt][kt], 0, 0, 0);
        // ks2 = 1
#pragma unroll
        for (int kt = 0; kt < 4; kt++) {
            int k = kt * 16 + c;
            bk[kt] = *(const short8*)(at_s + k * 64 + (((4 + g) ^ (k & 7)) << 3));
        }
#pragma unroll
        for (int dt = 0; dt < 2; dt++) {
            float4 f0 = ax[2 * dt + 0], f1 = ax[2 * dt + 1];
            uint4 u;
            u.x = bf16pair(f0.x, f0.y);
            u.y = bf16pair(f0.z, f0.w);
            u.z = bf16pair(f1.x, f1.y);
            u.w = bf16pair(f1.z, f1.w);
            short8 af1 = *(short8*)&u;
#pragma unroll
            for (int kt = 0; kt < 4; kt++)
                eacc[dt][kt] =
                    __builtin_amdgcn_mfma_f32_16x16x32_bf16(af1, bk[kt], eacc[dt][kt], 0, 0, 0);
        }
    }

    // ---- epilogue: partials P[block][k][d] in fp16 (d-contig uint2) ----
    __half* Pb = P + (size_t)blockIdx.x * (DD * KK);
#pragma unroll
    for (int dt = 0; dt < 2; dt++)
#pragma unroll
        for (int kt = 0; kt < 4; kt++) {
            int k = kt * 16 + c;
            int d0 = 32 * w + dt * 16 + 4 * g;
            f32x4 e = eacc[dt][kt];
            uint2 u;
            u.x = f16pair(e.x, e.y);
            u.y = f16pair(e.z, e.w);
            *(uint2*)(Pb + (size_t)k * DD + d0) = u;
        }

    // ---- per-block S: lane-sum over c, cross-nh combine via red_s ----
    // (red_s rewrite fenced vs last denom readers by E(p=3))
#pragma unroll
    for (int r = 0; r < 4; r++) {
        float v = s_acc[r];
        v += __shfl_xor(v, 1);
        v += __shfl_xor(v, 2);
        v += __shfl_xor(v, 4);
        v += __shfl_xor(v, 8);
        if (c == 0) red_s[w * 64 + 16 * kw + 4 * g + r] = v;  // [w][k]
    }
    __syncthreads();
    if (t < KK) {
        int k = t;
        int kw2 = k >> 4;
        Sp[blockIdx.x * 64 + k] = red_s[kw2 * 64 + k] + red_s[(kw2 + 4) * 64 + k];
    }
}

// ---------- finalize: sum 16 fp16 partials (f32 accum), subtract S*C ----------
__global__ __launch_bounds__(256) void k_fin(const __half* __restrict__ P,
                                             const float* __restrict__ Sp,
                                             const float* __restrict__ C,
                                             float* __restrict__ out) {
    int idx = blockIdx.x * 256 + threadIdx.x;  // 131072 total = 32 b * 64 k * 64 d4
    int b = idx >> 12;
    int r = idx & 4095;
    int k = r >> 6;
    int d0 = (r & 63) * 4;
    const __half* Pp = P + (size_t)b * 16 * (DD * KK) + k * DD + d0;
    const float* Sb = Sp + b * 16 * 64 + k;
    f32x4 e0 = (f32x4){0.f, 0.f, 0.f, 0.f};
    f32x4 e1 = (f32x4){0.f, 0.f, 0.f, 0.f};
    float s0 = 0.f, s1 = 0.f;
#pragma unroll
    for (int cc = 0; cc < 16; cc += 2) {
        uint2 v0 = *(const uint2*)(Pp + (size_t)cc * (DD * KK));
        uint2 v1 = *(const uint2*)(Pp + (size_t)(cc + 1) * (DD * KK));
        __half2 a0 = *(__half2*)&v0.x, a1 = *(__half2*)&v0.y;
        __half2 b0 = *(__half2*)&v1.x, b1 = *(__half2*)&v1.y;
        e0.x += __low2float(a0); e0.y += __high2float(a0);
        e0.z += __low2float(a1); e0.w += __high2float(a1);
        e1.x += __low2float(b0); e1.y += __high2float(b0);
        e1.z += __low2float(b1); e1.w += __high2float(b1);
        s0 += Sb[cc * 64];
        s1 += Sb[(cc + 1) * 64];
    }
    f32x4 cv = *(const f32x4*)(C + k * DD + d0);
    f32x4 e = e0 + e1;
    float s = s0 + s1;
    f32x4 o;
    o.x = e.x - s * cv.x;
    o.y = e.y - s * cv.y;
    o.z = e.z - s * cv.z;
    o.w = e.w - s * cv.w;
    *(f32x4*)(out + (size_t)(b * 64 + k) * DD + d0) = o;
}

// ---------- launch ----------
extern "C" void kernel_launch(void* const* d_in, const int* in_sizes, int n_in,
                              void* d_out, int out_size, void* d_ws, size_t ws_size,
                              hipStream_t stream) {
    const float* X = (const float*)d_in[0];
    const float* C = (const float*)d_in[1];
    float* out = (float*)d_out;
    unsigned char* ws = (unsigned char*)d_ws;

    // ws: Sp 512*64*4 = 131072 B | P 512*64*256*2 = 16777216 B (fp16 [block][k][d])
    float* Sp = (float*)ws;
    __half* P = (__half*)(ws + 131072);

    k_fused<<<512, 512, 0, stream>>>(X, C, P, Sp);
    k_fin<<<512, 256, 0, stream>>>(P, Sp, C, out);
}